// Round 13
// baseline (958.155 us; speedup 1.0000x reference)
//
#include <hip/hip_runtime.h>

// MoE: B=4,S=2048,D=1024,E=8,H=4096,K=2.  T = B*S = 8192 tokens.
// R13: R12 with gemm2 upgraded to BM=128 x BN=256, BK=64, 512 thr, 48KB LDS,
// launch_bounds(512,4) -> 2 blk/CU, 520 active blocks ~ 1.02 residency rounds,
// 87 FLOP/staged-byte (gemm1-equal). Fused atomic combine kept. Rest identical.
// ws usage ~352 MB.

#define T_TOK 8192
#define DDIM 1024
#define EEXP 8
#define HDIM 4096
#define RMAX 17408   // T*K + E*128 padding

typedef short short8 __attribute__((ext_vector_type(8)));
typedef float f32x4 __attribute__((ext_vector_type(4)));
typedef unsigned short ushort4v __attribute__((ext_vector_type(4)));
typedef unsigned int u32;

__device__ __forceinline__ unsigned short f2bf(float f) {
  unsigned u = __builtin_bit_cast(unsigned, f);
  return (unsigned short)((u + 0x7FFFu + ((u >> 16) & 1u)) >> 16);
}
__device__ __forceinline__ void gl_lds16(const void* g, void* l) {
  __builtin_amdgcn_global_load_lds((const u32 __attribute__((address_space(1)))*)g,
                                   (u32 __attribute__((address_space(3)))*)l, 16, 0, 0);
}
#define MFMA_BF16 __builtin_amdgcn_mfma_f32_16x16x32_bf16

// local prefix over 8 expert counts, 128-row alignment
__device__ __forceinline__ int base_of(const int* __restrict__ counts, int e) {
  int b = 0;
#pragma unroll
  for (int i = 0; i < EEXP; i++) if (i < e) b += (counts[i] + 127) & ~127;
  return b;
}

// ---- init: zero d_out, rowtok, rowp, counts, cursor ------------------------
__global__ void k_init(int* __restrict__ rowtok, float* __restrict__ rowp,
                       int* __restrict__ counts, int* __restrict__ cursor,
                       float4* __restrict__ out4) {
  int i = blockIdx.x * 256 + threadIdx.x;      // grid 8192 -> 2,097,152 = T*D/4
  out4[i] = float4{0.f, 0.f, 0.f, 0.f};
  if (i < RMAX) { rowtok[i] = 0; rowp[i] = 0.f; }
  if (i < EEXP) { counts[i] = 0; cursor[i] = 0; }
}

// ---- weights: f32 [E][K][N] -> bf16 swizzled 16KB tiles, all fused ---------
__global__ void k_convert_all(const float* __restrict__ w1, const float* __restrict__ w2,
                              const float* __restrict__ wp,
                              unsigned short* __restrict__ w1s, unsigned short* __restrict__ w2s,
                              unsigned short* __restrict__ wps) {
  __shared__ float lbuf[64 * 129];
  int bid = blockIdx.x;                 // 0..12287
  int seg = bid >> 12;
  int t = bid & 4095;
  const float* src; unsigned short* dst; int N, K, ct, kt, e;
  e = t >> 9;
  if (seg == 0)      { src = w1; dst = w1s; N = HDIM; K = DDIM; ct = (t >> 4) & 31; kt = t & 15; }
  else if (seg == 1) { src = w2; dst = w2s; N = HDIM; K = DDIM; ct = (t >> 4) & 31; kt = t & 15; }
  else               { src = wp; dst = wps; N = DDIM; K = HDIM; ct = (t >> 6) & 7;  kt = t & 63; }
  int tid = threadIdx.x;
  const float* s = src + (size_t)e * K * N + (size_t)(kt * 64) * N + ct * 128;
#pragma unroll
  for (int q = 0; q < 8; q++) {
    int idx = q * 256 + tid;
    int row = idx >> 5, c4 = (idx & 31) * 4;
    float4 v = *(const float4*)(s + (size_t)row * N + c4);
    lbuf[row * 129 + c4 + 0] = v.x;
    lbuf[row * 129 + c4 + 1] = v.y;
    lbuf[row * 129 + c4 + 2] = v.z;
    lbuf[row * 129 + c4 + 3] = v.w;
  }
  __syncthreads();
  unsigned short* dt = dst + ((size_t)(e * (N / 128) + ct) * (K / 64) + kt) * 8192;
#pragma unroll
  for (int q = 0; q < 4; q++) {
    int idx = q * 256 + tid;
    int kc = idx & 7, n = idx >> 3;
    short8 o;
#pragma unroll
    for (int j = 0; j < 8; j++) o[j] = (short)f2bf(lbuf[(kc * 8 + j) * 129 + n]);
    int byte = (n * 128 + kc * 16) ^ ((n & 7) << 4);
    *(short8*)((char*)dt + byte) = o;
  }
}

// ---- gating (+ fused x->bf16) ----------------------------------------------
__launch_bounds__(256)
__global__ void k_gate(const float* __restrict__ x, const float* __restrict__ gw,
                       const float* __restrict__ nwt, const float* __restrict__ noi,
                       int* __restrict__ tki, float* __restrict__ tkp,
                       int* __restrict__ counts, unsigned short* __restrict__ xb) {
  __shared__ float gwT[8][1024];
  int tid = threadIdx.x;
#pragma unroll
  for (int q = 0; q < 32; q++) {
    int flat = q * 256 + tid;
    gwT[flat & 7][flat >> 3] = gw[flat];
  }
  __syncthreads();
  int wave = tid >> 6, l = tid & 63;
  int t = blockIdx.x * 4 + wave;
  float acc[8] = {0.f, 0.f, 0.f, 0.f, 0.f, 0.f, 0.f, 0.f};
  const float4* xr = (const float4*)(x + (size_t)t * DDIM);
#pragma unroll
  for (int i = 0; i < 4; i++) {
    float4 xv = xr[l + i * 64];
    int d0 = (l + i * 64) * 4;
    ushort4v o;
    o.x = f2bf(xv.x); o.y = f2bf(xv.y); o.z = f2bf(xv.z); o.w = f2bf(xv.w);
    *(ushort4v*)(xb + (size_t)t * DDIM + d0) = o;
#pragma unroll
    for (int e = 0; e < 8; e++) {
      float4 gv = *(const float4*)&gwT[e][d0];
      acc[e] += xv.x * gv.x + xv.y * gv.y + xv.z * gv.z + xv.w * gv.w;
    }
  }
#pragma unroll
  for (int s = 1; s < 64; s <<= 1) {
#pragma unroll
    for (int e = 0; e < 8; e++) acc[e] += __shfl_xor(acc[e], s, 64);
  }
  if (l == 0) {
    float nl[8];
#pragma unroll
    for (int e = 0; e < 8; e++) nl[e] = acc[e] + noi[t * 8 + e] * nwt[e];
    int i0 = 0; float v0 = nl[0];
#pragma unroll
    for (int e = 1; e < 8; e++) if (nl[e] > v0) { v0 = nl[e]; i0 = e; }
    int i1 = -1; float v1 = -3.4e38f;
#pragma unroll
    for (int e = 0; e < 8; e++) if (e != i0 && nl[e] > v1) { v1 = nl[e]; i1 = e; }
    float ex = __expf(v1 - v0);
    float p0 = 1.f / (1.f + ex);
    float p1 = ex * p0;
    tki[2 * t] = i0; tki[2 * t + 1] = i1;
    tkp[2 * t] = p0; tkp[2 * t + 1] = p1;
    atomicAdd(&counts[i0], 1);
    atomicAdd(&counts[i1], 1);
  }
}

// ---- scatter (rowtok + rowp), prefix computed locally ----------------------
__global__ void k_scatter(const int* __restrict__ tki, const float* __restrict__ tkp,
                          const int* __restrict__ counts, int* __restrict__ cursor,
                          int* __restrict__ rowtok, float* __restrict__ rowp) {
  int t = blockIdx.x * 256 + threadIdx.x;
  if (t >= T_TOK) return;
#pragma unroll
  for (int k = 0; k < 2; k++) {
    int e = tki[2 * t + k];
    int pos = atomicAdd(&cursor[e], 1);
    int row = base_of(counts, e) + pos;
    rowtok[row] = t;
    rowp[row] = tkp[2 * t + k];
  }
}

// ---- GEMM1 (R2 structure, 2D grid): h = (Xg@w1+b1)*silu(Xg@w2+b2) ----------
__launch_bounds__(256, 2)
__global__ void k_gemm1(const unsigned short* __restrict__ xb,
                        const unsigned short* __restrict__ w1s, const unsigned short* __restrict__ w2s,
                        const float* __restrict__ b1g, const float* __restrict__ b2g,
                        const int* __restrict__ counts,
                        const int* __restrict__ rowtok,
                        unsigned short* __restrict__ hout) {
  int e = blockIdx.y >> 6;
  int rt = blockIdx.y & 63;
  int cnt = counts[e];
  if (rt >= ((cnt + 127) >> 7)) return;
  int ct = blockIdx.x;                         // 0..31 over H
  int row0 = base_of(counts, e) + rt * 128;
  int col0 = ct * 128;

  __shared__ char smem[49152];      // A[128][64] | B1t | B2t (bf16, swizzled)
  __shared__ int s_tok[128];
  __shared__ float s_b1[128], s_b2[128];

  int tid = threadIdx.x;
  if (tid < 128) {
    s_tok[tid] = rowtok[row0 + tid];
    s_b1[tid] = b1g[e * HDIM + col0 + tid];
    s_b2[tid] = b2g[e * HDIM + col0 + tid];
  }
  __syncthreads();

  int wave = tid >> 6, l = tid & 63;
  int wr = (wave >> 1) << 6, wc = (wave & 1) << 6;
  int g = l >> 4, ln = l & 15;

  int sr[4], stok[4], sxor[4];
#pragma unroll
  for (int q = 0; q < 4; q++) {
    int flat = q * 256 + tid;
    sr[q] = flat;
    int r = flat >> 3, c = flat & 7;
    stok[q] = s_tok[r];
    sxor[q] = (c ^ (r & 7)) << 3;
  }

  f32x4 zero = {0.f, 0.f, 0.f, 0.f};
  f32x4 acc_a[4][4], acc_b[4][4];
#pragma unroll
  for (int m = 0; m < 4; m++)
#pragma unroll
    for (int n = 0; n < 4; n++) { acc_a[m][n] = zero; acc_b[m][n] = zero; }

  const unsigned short* w1t = w1s + ((size_t)(e * 32 + ct) * 16) * 8192;
  const unsigned short* w2t = w2s + ((size_t)(e * 32 + ct) * 16) * 8192;

  for (int kt = 0; kt < 16; kt++) {
#pragma unroll
    for (int q = 0; q < 4; q++) {
      gl_lds16(xb + (size_t)stok[q] * DDIM + kt * 64 + sxor[q], smem + sr[q] * 16);
      gl_lds16(w1t + (size_t)kt * 8192 + sr[q] * 8, smem + 16384 + sr[q] * 16);
      gl_lds16(w2t + (size_t)kt * 8192 + sr[q] * 8, smem + 32768 + sr[q] * 16);
    }
    __syncthreads();
#pragma unroll
    for (int ks = 0; ks < 2; ks++) {
      int kb = ks * 64 + g * 16;
      short8 af[4], bf1[4], bf2[4];
#pragma unroll
      for (int m = 0; m < 4; m++) {
        int r = wr + m * 16 + ln;
        af[m] = *(const short8*)(smem + ((r * 128 + kb) ^ ((r & 7) << 4)));
      }
#pragma unroll
      for (int n = 0; n < 4; n++) {
        int r = wc + n * 16 + ln;
        int byte = (r * 128 + kb) ^ ((r & 7) << 4);
        bf1[n] = *(const short8*)(smem + 16384 + byte);
        bf2[n] = *(const short8*)(smem + 32768 + byte);
      }
#pragma unroll
      for (int m = 0; m < 4; m++)
#pragma unroll
        for (int n = 0; n < 4; n++) {
          acc_a[m][n] = MFMA_BF16(af[m], bf1[n], acc_a[m][n], 0, 0, 0);
          acc_b[m][n] = MFMA_BF16(af[m], bf2[n], acc_b[m][n], 0, 0, 0);
        }
    }
    __syncthreads();
  }
  // epilogue: SwiGLU -> bf16 tile in LDS, then coalesced stores
  unsigned short* ht = (unsigned short*)smem;
#pragma unroll
  for (int m = 0; m < 4; m++)
#pragma unroll
    for (int n = 0; n < 4; n++)
#pragma unroll
      for (int r = 0; r < 4; r++) {
        int row = wr + m * 16 + g * 4 + r;
        int col = wc + n * 16 + ln;
        float a = acc_a[m][n][r] + s_b1[col];
        float b = acc_b[m][n][r] + s_b2[col];
        float hv = a * (b / (1.f + __expf(-b)));
        ht[row * 128 + col] = f2bf(hv);
      }
  __syncthreads();
#pragma unroll
  for (int q = 0; q < 8; q++) {
    int idx = q * 256 + tid;
    int row = idx >> 4, chunk = idx & 15;
    short8 v = *(const short8*)(smem + idx * 16);
    *(short8*)(hout + (size_t)(row0 + row) * HDIM + col0 + chunk * 8) = v;
  }
}

// ---- GEMM2: BM=128, BN=256, BK=64, 512 thr, 2 blk/CU, fused atomic combine -
__launch_bounds__(512, 4)
__global__ void k_gemm2(const unsigned short* __restrict__ hin,
                        const unsigned short* __restrict__ wps, const float* __restrict__ bpg,
                        const int* __restrict__ counts,
                        const int* __restrict__ rowtok, const float* __restrict__ rowp,
                        float* __restrict__ outp) {
  int e = blockIdx.y >> 6;
  int rt = blockIdx.y & 63;
  int cnt = counts[e];
  if (rt >= ((cnt + 127) >> 7)) return;
  int ct = blockIdx.x;              // 0..3 over D (256 cols)
  int row0 = base_of(counts, e) + rt * 128;
  int col0 = ct * 256;

  __shared__ char smem[49152];      // A[128][64] 16KB | B 2x[128][64] 32KB
  __shared__ int s_tok[128];
  __shared__ float s_p[128], s_bp[256];
  int tid = threadIdx.x;
  if (tid < 128) {
    s_tok[tid] = rowtok[row0 + tid];
    s_p[tid] = rowp[row0 + tid];
  }
  if (tid < 256) s_bp[tid] = bpg[e * DDIM + col0 + tid];
  __syncthreads();

  int wave = tid >> 6, l = tid & 63;
  int wm = wave >> 2, wn = wave & 3;          // 2M x 4N: wave tile 64 x 64
  int g = l >> 4, ln = l & 15;

  // A staging: 1024 chunks, 2/thread
  int a_sr[2], a_row[2], a_xor[2];
#pragma unroll
  for (int q = 0; q < 2; q++) {
    int flat = q * 512 + tid;
    a_sr[q] = flat;
    int r = flat >> 3, c = flat & 7;
    a_row[q] = row0 + r;
    a_xor[q] = (c ^ (r & 7)) << 3;
  }

  f32x4 zero = {0.f, 0.f, 0.f, 0.f};
  f32x4 acc[4][4];
#pragma unroll
  for (int m = 0; m < 4; m++)
#pragma unroll
    for (int n = 0; n < 4; n++) acc[m][n] = zero;

  const unsigned short* wpt0 = wps + ((size_t)(e * 8 + ct * 2 + 0) * 64) * 8192;
  const unsigned short* wpt1 = wps + ((size_t)(e * 8 + ct * 2 + 1) * 64) * 8192;

  for (int kt = 0; kt < 64; kt++) {
#pragma unroll
    for (int q = 0; q < 2; q++)
      gl_lds16(hin + (size_t)a_row[q] * HDIM + kt * 64 + a_xor[q], smem + a_sr[q] * 16);
#pragma unroll
    for (int q = 0; q < 2; q++) {
      int j = q * 512 + tid;          // 1024 chunks per subtile
      gl_lds16(wpt0 + (size_t)kt * 8192 + j * 8, smem + 16384 + j * 16);
      gl_lds16(wpt1 + (size_t)kt * 8192 + j * 8, smem + 32768 + j * 16);
    }
    __syncthreads();
#pragma unroll
    for (int ks = 0; ks < 2; ks++) {
      int kb = ks * 64 + g * 16;
      short8 af[4], bfr[4];
#pragma unroll
      for (int m = 0; m < 4; m++) {
        int r = wm * 64 + m * 16 + ln;
        af[m] = *(const short8*)(smem + ((r * 128 + kb) ^ ((r & 7) << 4)));
      }
#pragma unroll
      for (int n = 0; n < 4; n++) {
        int ncol = wn * 64 + n * 16 + ln;   // 0..255
        int sub = ncol >> 7, rr = ncol & 127;
        bfr[n] = *(const short8*)(smem + 16384 + sub * 16384 +
                                  ((rr * 128 + kb) ^ ((rr & 7) << 4)));
      }
#pragma unroll
      for (int m = 0; m < 4; m++)
#pragma unroll
        for (int n = 0; n < 4; n++)
          acc[m][n] = MFMA_BF16(af[m], bfr[n], acc[m][n], 0, 0, 0);
    }
    __syncthreads();
  }

  // fused combine: out[tok, col] += p * (acc + bp)   (pad rows have p == 0)
#pragma unroll
  for (int m = 0; m < 4; m++)
#pragma unroll
    for (int r = 0; r < 4; r++) {
      int row = wm * 64 + m * 16 + g * 4 + r;
      float p = s_p[row];
      if (p != 0.f) {
        size_t obase = (size_t)s_tok[row] * DDIM + col0;
#pragma unroll
        for (int n = 0; n < 4; n++) {
          int col = wn * 64 + n * 16 + ln;
          atomicAdd(&outp[obase + col], p * (acc[m][n][r] + s_bp[col]));
        }
      }
    }
}

extern "C" void kernel_launch(void* const* d_in, const int* in_sizes, int n_in,
                              void* d_out, int out_size, void* d_ws, size_t ws_size,
                              hipStream_t stream) {
  const float* x   = (const float*)d_in[0];
  const float* gw  = (const float*)d_in[1];
  const float* nwt = (const float*)d_in[2];
  const float* noi = (const float*)d_in[3];
  const float* w1  = (const float*)d_in[4];
  const float* b1  = (const float*)d_in[5];
  const float* w2  = (const float*)d_in[6];
  const float* b2  = (const float*)d_in[7];
  const float* wp  = (const float*)d_in[8];
  const float* bp  = (const float*)d_in[9];
  float* outp = (float*)d_out;
  char* ws = (char*)d_ws;

  constexpr size_t SZ_W = (size_t)EEXP * DDIM * HDIM * 2;          // 64 MB each
  constexpr size_t OFF_XB  = 0;
  constexpr size_t OFF_W1S = OFF_XB + (size_t)T_TOK * DDIM * 2;
  constexpr size_t OFF_W2S = OFF_W1S + SZ_W;
  constexpr size_t OFF_WPS = OFF_W2S + SZ_W;
  constexpr size_t OFF_H   = OFF_WPS + SZ_W;
  constexpr size_t OFF_RT  = OFF_H + (size_t)RMAX * HDIM * 2;
  constexpr size_t OFF_RP  = OFF_RT + (size_t)RMAX * 4;
  constexpr size_t OFF_TKI = OFF_RP + (size_t)RMAX * 4;
  constexpr size_t OFF_TKP = OFF_TKI + (size_t)T_TOK * 2 * 4;
  constexpr size_t OFF_CNT = OFF_TKP + (size_t)T_TOK * 2 * 4;
  constexpr size_t OFF_CUR = OFF_CNT + 256;
  // total ~352 MB

  unsigned short* xb  = (unsigned short*)(ws + OFF_XB);
  unsigned short* w1s = (unsigned short*)(ws + OFF_W1S);
  unsigned short* w2s = (unsigned short*)(ws + OFF_W2S);
  unsigned short* wps = (unsigned short*)(ws + OFF_WPS);
  unsigned short* h   = (unsigned short*)(ws + OFF_H);
  int*   rowtok = (int*)(ws + OFF_RT);
  float* rowp   = (float*)(ws + OFF_RP);
  int*   tki    = (int*)(ws + OFF_TKI);
  float* tkp    = (float*)(ws + OFF_TKP);
  int*   counts = (int*)(ws + OFF_CNT);
  int*   cursor = (int*)(ws + OFF_CUR);

  dim3 blk(256);
  k_init<<<dim3(8192), blk, 0, stream>>>(rowtok, rowp, counts, cursor, (float4*)outp);
  k_gate<<<dim3(T_TOK / 4), blk, 0, stream>>>(x, gw, nwt, noi, tki, tkp, counts, xb);
  k_convert_all<<<dim3(12288), blk, 0, stream>>>(w1, w2, wp, w1s, w2s, wps);
  k_scatter<<<dim3(T_TOK / 256), blk, 0, stream>>>(tki, tkp, counts, cursor, rowtok, rowp);
  k_gemm1<<<dim3(HDIM / 128, EEXP * 64), blk, 0, stream>>>(xb, w1s, w2s, b1, b2, counts, rowtok, h);
  k_gemm2<<<dim3(DDIM / 256, EEXP * 64), dim3(512), 0, stream>>>(h, wps, bp, counts, rowtok, rowp, outp);
  (void)in_sizes; (void)n_in; (void)out_size; (void)ws_size;
}

// Round 14
// 928.321 us; speedup vs baseline: 1.0321x; 1.0321x over previous
//
#include <hip/hip_runtime.h>

// MoE: B=4,S=2048,D=1024,E=8,H=4096,K=2.  T = B*S = 8192 tokens.
// R14 (final lock-in = R12): measured-best configuration.
//  - gemm1: R2 structure (128^2 tiles, 256 thr, 2D grid, global_load_lds
//    staging of pre-swizzled bf16 weight tiles) — 349 us, m97-structure ceiling.
//  - gemm2: fused-atomic 128^2 (out += p*(h@wp+bp)), launch_bounds(256,4).
//  - converts fused into one launch; prefix folded into consumers; 6 launches.
// ws usage ~352 MB.

#define T_TOK 8192
#define DDIM 1024
#define EEXP 8
#define HDIM 4096
#define RMAX 17408   // T*K + E*128 padding

typedef short short8 __attribute__((ext_vector_type(8)));
typedef float f32x4 __attribute__((ext_vector_type(4)));
typedef unsigned short ushort4v __attribute__((ext_vector_type(4)));
typedef unsigned int u32;

__device__ __forceinline__ unsigned short f2bf(float f) {
  unsigned u = __builtin_bit_cast(unsigned, f);
  return (unsigned short)((u + 0x7FFFu + ((u >> 16) & 1u)) >> 16);
}
__device__ __forceinline__ void gl_lds16(const void* g, void* l) {
  __builtin_amdgcn_global_load_lds((const u32 __attribute__((address_space(1)))*)g,
                                   (u32 __attribute__((address_space(3)))*)l, 16, 0, 0);
}
#define MFMA_BF16 __builtin_amdgcn_mfma_f32_16x16x32_bf16

// local prefix over 8 expert counts, 128-row alignment
__device__ __forceinline__ int base_of(const int* __restrict__ counts, int e) {
  int b = 0;
#pragma unroll
  for (int i = 0; i < EEXP; i++) if (i < e) b += (counts[i] + 127) & ~127;
  return b;
}

// ---- init: zero d_out, rowtok, rowp, counts, cursor ------------------------
__global__ void k_init(int* __restrict__ rowtok, float* __restrict__ rowp,
                       int* __restrict__ counts, int* __restrict__ cursor,
                       float4* __restrict__ out4) {
  int i = blockIdx.x * 256 + threadIdx.x;      // grid 8192 -> 2,097,152 = T*D/4
  out4[i] = float4{0.f, 0.f, 0.f, 0.f};
  if (i < RMAX) { rowtok[i] = 0; rowp[i] = 0.f; }
  if (i < EEXP) { counts[i] = 0; cursor[i] = 0; }
}

// ---- weights: f32 [E][K][N] -> bf16 swizzled 16KB tiles, all fused ---------
__global__ void k_convert_all(const float* __restrict__ w1, const float* __restrict__ w2,
                              const float* __restrict__ wp,
                              unsigned short* __restrict__ w1s, unsigned short* __restrict__ w2s,
                              unsigned short* __restrict__ wps) {
  __shared__ float lbuf[64 * 129];
  int bid = blockIdx.x;                 // 0..12287
  int seg = bid >> 12;
  int t = bid & 4095;
  const float* src; unsigned short* dst; int N, K, ct, kt, e;
  e = t >> 9;
  if (seg == 0)      { src = w1; dst = w1s; N = HDIM; K = DDIM; ct = (t >> 4) & 31; kt = t & 15; }
  else if (seg == 1) { src = w2; dst = w2s; N = HDIM; K = DDIM; ct = (t >> 4) & 31; kt = t & 15; }
  else               { src = wp; dst = wps; N = DDIM; K = HDIM; ct = (t >> 6) & 7;  kt = t & 63; }
  int tid = threadIdx.x;
  const float* s = src + (size_t)e * K * N + (size_t)(kt * 64) * N + ct * 128;
#pragma unroll
  for (int q = 0; q < 8; q++) {
    int idx = q * 256 + tid;
    int row = idx >> 5, c4 = (idx & 31) * 4;
    float4 v = *(const float4*)(s + (size_t)row * N + c4);
    lbuf[row * 129 + c4 + 0] = v.x;
    lbuf[row * 129 + c4 + 1] = v.y;
    lbuf[row * 129 + c4 + 2] = v.z;
    lbuf[row * 129 + c4 + 3] = v.w;
  }
  __syncthreads();
  unsigned short* dt = dst + ((size_t)(e * (N / 128) + ct) * (K / 64) + kt) * 8192;
#pragma unroll
  for (int q = 0; q < 4; q++) {
    int idx = q * 256 + tid;
    int kc = idx & 7, n = idx >> 3;
    short8 o;
#pragma unroll
    for (int j = 0; j < 8; j++) o[j] = (short)f2bf(lbuf[(kc * 8 + j) * 129 + n]);
    int byte = (n * 128 + kc * 16) ^ ((n & 7) << 4);
    *(short8*)((char*)dt + byte) = o;
  }
}

// ---- gating (+ fused x->bf16) ----------------------------------------------
__launch_bounds__(256)
__global__ void k_gate(const float* __restrict__ x, const float* __restrict__ gw,
                       const float* __restrict__ nwt, const float* __restrict__ noi,
                       int* __restrict__ tki, float* __restrict__ tkp,
                       int* __restrict__ counts, unsigned short* __restrict__ xb) {
  __shared__ float gwT[8][1024];
  int tid = threadIdx.x;
#pragma unroll
  for (int q = 0; q < 32; q++) {
    int flat = q * 256 + tid;
    gwT[flat & 7][flat >> 3] = gw[flat];
  }
  __syncthreads();
  int wave = tid >> 6, l = tid & 63;
  int t = blockIdx.x * 4 + wave;
  float acc[8] = {0.f, 0.f, 0.f, 0.f, 0.f, 0.f, 0.f, 0.f};
  const float4* xr = (const float4*)(x + (size_t)t * DDIM);
#pragma unroll
  for (int i = 0; i < 4; i++) {
    float4 xv = xr[l + i * 64];
    int d0 = (l + i * 64) * 4;
    ushort4v o;
    o.x = f2bf(xv.x); o.y = f2bf(xv.y); o.z = f2bf(xv.z); o.w = f2bf(xv.w);
    *(ushort4v*)(xb + (size_t)t * DDIM + d0) = o;
#pragma unroll
    for (int e = 0; e < 8; e++) {
      float4 gv = *(const float4*)&gwT[e][d0];
      acc[e] += xv.x * gv.x + xv.y * gv.y + xv.z * gv.z + xv.w * gv.w;
    }
  }
#pragma unroll
  for (int s = 1; s < 64; s <<= 1) {
#pragma unroll
    for (int e = 0; e < 8; e++) acc[e] += __shfl_xor(acc[e], s, 64);
  }
  if (l == 0) {
    float nl[8];
#pragma unroll
    for (int e = 0; e < 8; e++) nl[e] = acc[e] + noi[t * 8 + e] * nwt[e];
    int i0 = 0; float v0 = nl[0];
#pragma unroll
    for (int e = 1; e < 8; e++) if (nl[e] > v0) { v0 = nl[e]; i0 = e; }
    int i1 = -1; float v1 = -3.4e38f;
#pragma unroll
    for (int e = 0; e < 8; e++) if (e != i0 && nl[e] > v1) { v1 = nl[e]; i1 = e; }
    float ex = __expf(v1 - v0);
    float p0 = 1.f / (1.f + ex);
    float p1 = ex * p0;
    tki[2 * t] = i0; tki[2 * t + 1] = i1;
    tkp[2 * t] = p0; tkp[2 * t + 1] = p1;
    atomicAdd(&counts[i0], 1);
    atomicAdd(&counts[i1], 1);
  }
}

// ---- scatter (rowtok + rowp), prefix computed locally ----------------------
__global__ void k_scatter(const int* __restrict__ tki, const float* __restrict__ tkp,
                          const int* __restrict__ counts, int* __restrict__ cursor,
                          int* __restrict__ rowtok, float* __restrict__ rowp) {
  int t = blockIdx.x * 256 + threadIdx.x;
  if (t >= T_TOK) return;
#pragma unroll
  for (int k = 0; k < 2; k++) {
    int e = tki[2 * t + k];
    int pos = atomicAdd(&cursor[e], 1);
    int row = base_of(counts, e) + pos;
    rowtok[row] = t;
    rowp[row] = tkp[2 * t + k];
  }
}

// ---- GEMM1 (R2 structure, 2D grid): h = (Xg@w1+b1)*silu(Xg@w2+b2) ----------
__launch_bounds__(256, 2)
__global__ void k_gemm1(const unsigned short* __restrict__ xb,
                        const unsigned short* __restrict__ w1s, const unsigned short* __restrict__ w2s,
                        const float* __restrict__ b1g, const float* __restrict__ b2g,
                        const int* __restrict__ counts,
                        const int* __restrict__ rowtok,
                        unsigned short* __restrict__ hout) {
  int e = blockIdx.y >> 6;
  int rt = blockIdx.y & 63;
  int cnt = counts[e];
  if (rt >= ((cnt + 127) >> 7)) return;
  int ct = blockIdx.x;                         // 0..31 over H
  int row0 = base_of(counts, e) + rt * 128;
  int col0 = ct * 128;

  __shared__ char smem[49152];      // A[128][64] | B1t | B2t (bf16, swizzled)
  __shared__ int s_tok[128];
  __shared__ float s_b1[128], s_b2[128];

  int tid = threadIdx.x;
  if (tid < 128) {
    s_tok[tid] = rowtok[row0 + tid];
    s_b1[tid] = b1g[e * HDIM + col0 + tid];
    s_b2[tid] = b2g[e * HDIM + col0 + tid];
  }
  __syncthreads();

  int wave = tid >> 6, l = tid & 63;
  int wr = (wave >> 1) << 6, wc = (wave & 1) << 6;
  int g = l >> 4, ln = l & 15;

  int sr[4], stok[4], sxor[4];
#pragma unroll
  for (int q = 0; q < 4; q++) {
    int flat = q * 256 + tid;
    sr[q] = flat;
    int r = flat >> 3, c = flat & 7;
    stok[q] = s_tok[r];
    sxor[q] = (c ^ (r & 7)) << 3;
  }

  f32x4 zero = {0.f, 0.f, 0.f, 0.f};
  f32x4 acc_a[4][4], acc_b[4][4];
#pragma unroll
  for (int m = 0; m < 4; m++)
#pragma unroll
    for (int n = 0; n < 4; n++) { acc_a[m][n] = zero; acc_b[m][n] = zero; }

  const unsigned short* w1t = w1s + ((size_t)(e * 32 + ct) * 16) * 8192;
  const unsigned short* w2t = w2s + ((size_t)(e * 32 + ct) * 16) * 8192;

  for (int kt = 0; kt < 16; kt++) {
#pragma unroll
    for (int q = 0; q < 4; q++) {
      gl_lds16(xb + (size_t)stok[q] * DDIM + kt * 64 + sxor[q], smem + sr[q] * 16);
      gl_lds16(w1t + (size_t)kt * 8192 + sr[q] * 8, smem + 16384 + sr[q] * 16);
      gl_lds16(w2t + (size_t)kt * 8192 + sr[q] * 8, smem + 32768 + sr[q] * 16);
    }
    __syncthreads();
#pragma unroll
    for (int ks = 0; ks < 2; ks++) {
      int kb = ks * 64 + g * 16;
      short8 af[4], bf1[4], bf2[4];
#pragma unroll
      for (int m = 0; m < 4; m++) {
        int r = wr + m * 16 + ln;
        af[m] = *(const short8*)(smem + ((r * 128 + kb) ^ ((r & 7) << 4)));
      }
#pragma unroll
      for (int n = 0; n < 4; n++) {
        int r = wc + n * 16 + ln;
        int byte = (r * 128 + kb) ^ ((r & 7) << 4);
        bf1[n] = *(const short8*)(smem + 16384 + byte);
        bf2[n] = *(const short8*)(smem + 32768 + byte);
      }
#pragma unroll
      for (int m = 0; m < 4; m++)
#pragma unroll
        for (int n = 0; n < 4; n++) {
          acc_a[m][n] = MFMA_BF16(af[m], bf1[n], acc_a[m][n], 0, 0, 0);
          acc_b[m][n] = MFMA_BF16(af[m], bf2[n], acc_b[m][n], 0, 0, 0);
        }
    }
    __syncthreads();
  }
  // epilogue: SwiGLU -> bf16 tile in LDS, then coalesced stores
  unsigned short* ht = (unsigned short*)smem;
#pragma unroll
  for (int m = 0; m < 4; m++)
#pragma unroll
    for (int n = 0; n < 4; n++)
#pragma unroll
      for (int r = 0; r < 4; r++) {
        int row = wr + m * 16 + g * 4 + r;
        int col = wc + n * 16 + ln;
        float a = acc_a[m][n][r] + s_b1[col];
        float b = acc_b[m][n][r] + s_b2[col];
        float hv = a * (b / (1.f + __expf(-b)));
        ht[row * 128 + col] = f2bf(hv);
      }
  __syncthreads();
#pragma unroll
  for (int q = 0; q < 8; q++) {
    int idx = q * 256 + tid;
    int row = idx >> 4, chunk = idx & 15;
    short8 v = *(const short8*)(smem + idx * 16);
    *(short8*)(hout + (size_t)(row0 + row) * HDIM + col0 + chunk * 8) = v;
  }
}

// ---- GEMM2 (fused-atomic combine), 4 blk/CU --------------------------------
__launch_bounds__(256, 4)
__global__ void k_gemm2(const unsigned short* __restrict__ hin,
                        const unsigned short* __restrict__ wps, const float* __restrict__ bpg,
                        const int* __restrict__ counts,
                        const int* __restrict__ rowtok, const float* __restrict__ rowp,
                        float* __restrict__ outp) {
  int e = blockIdx.y >> 6;
  int rt = blockIdx.y & 63;
  int cnt = counts[e];
  if (rt >= ((cnt + 127) >> 7)) return;
  int ct = blockIdx.x;              // 0..7 over D
  int row0 = base_of(counts, e) + rt * 128;
  int col0 = ct * 128;

  __shared__ char smem[32768];
  __shared__ int s_tok[128];
  __shared__ float s_p[128], s_bp[128];
  int tid = threadIdx.x;
  if (tid < 128) {
    s_tok[tid] = rowtok[row0 + tid];
    s_p[tid] = rowp[row0 + tid];
    s_bp[tid] = bpg[e * DDIM + col0 + tid];
  }
  __syncthreads();

  int wave = tid >> 6, l = tid & 63;
  int wr = (wave >> 1) << 6, wc = (wave & 1) << 6;
  int g = l >> 4, ln = l & 15;

  int sr[4], srow[4], sxor[4];
#pragma unroll
  for (int q = 0; q < 4; q++) {
    int flat = q * 256 + tid;
    sr[q] = flat;
    int r = flat >> 3, c = flat & 7;
    srow[q] = row0 + r;
    sxor[q] = (c ^ (r & 7)) << 3;
  }

  f32x4 zero = {0.f, 0.f, 0.f, 0.f};
  f32x4 acc[4][4];
#pragma unroll
  for (int m = 0; m < 4; m++)
#pragma unroll
    for (int n = 0; n < 4; n++) acc[m][n] = zero;

  const unsigned short* wpt = wps + ((size_t)(e * 8 + ct) * 64) * 8192;

  for (int kt = 0; kt < 64; kt++) {
#pragma unroll
    for (int q = 0; q < 4; q++) {
      gl_lds16(hin + (size_t)srow[q] * HDIM + kt * 64 + sxor[q], smem + sr[q] * 16);
      gl_lds16(wpt + (size_t)kt * 8192 + sr[q] * 8, smem + 16384 + sr[q] * 16);
    }
    __syncthreads();
#pragma unroll
    for (int ks = 0; ks < 2; ks++) {
      int kb = ks * 64 + g * 16;
      short8 af[4], bfr[4];
#pragma unroll
      for (int m = 0; m < 4; m++) {
        int r = wr + m * 16 + ln;
        af[m] = *(const short8*)(smem + ((r * 128 + kb) ^ ((r & 7) << 4)));
      }
#pragma unroll
      for (int n = 0; n < 4; n++) {
        int r = wc + n * 16 + ln;
        bfr[n] = *(const short8*)(smem + 16384 + ((r * 128 + kb) ^ ((r & 7) << 4)));
      }
#pragma unroll
      for (int m = 0; m < 4; m++)
#pragma unroll
        for (int n = 0; n < 4; n++)
          acc[m][n] = MFMA_BF16(af[m], bfr[n], acc[m][n], 0, 0, 0);
    }
    __syncthreads();
  }

  // fused combine: out[tok, col] += p * (acc + bp)   (pad rows have p == 0)
#pragma unroll
  for (int m = 0; m < 4; m++)
#pragma unroll
    for (int r = 0; r < 4; r++) {
      int row = wr + m * 16 + g * 4 + r;
      float p = s_p[row];
      if (p != 0.f) {
        size_t obase = (size_t)s_tok[row] * DDIM + col0;
#pragma unroll
        for (int n = 0; n < 4; n++) {
          int col = wc + n * 16 + ln;
          atomicAdd(&outp[obase + col], p * (acc[m][n][r] + s_bp[col]));
        }
      }
    }
}

extern "C" void kernel_launch(void* const* d_in, const int* in_sizes, int n_in,
                              void* d_out, int out_size, void* d_ws, size_t ws_size,
                              hipStream_t stream) {
  const float* x   = (const float*)d_in[0];
  const float* gw  = (const float*)d_in[1];
  const float* nwt = (const float*)d_in[2];
  const float* noi = (const float*)d_in[3];
  const float* w1  = (const float*)d_in[4];
  const float* b1  = (const float*)d_in[5];
  const float* w2  = (const float*)d_in[6];
  const float* b2  = (const float*)d_in[7];
  const float* wp  = (const float*)d_in[8];
  const float* bp  = (const float*)d_in[9];
  float* outp = (float*)d_out;
  char* ws = (char*)d_ws;

  constexpr size_t SZ_W = (size_t)EEXP * DDIM * HDIM * 2;          // 64 MB each
  constexpr size_t OFF_XB  = 0;
  constexpr size_t OFF_W1S = OFF_XB + (size_t)T_TOK * DDIM * 2;
  constexpr size_t OFF_W2S = OFF_W1S + SZ_W;
  constexpr size_t OFF_WPS = OFF_W2S + SZ_W;
  constexpr size_t OFF_H   = OFF_WPS + SZ_W;
  constexpr size_t OFF_RT  = OFF_H + (size_t)RMAX * HDIM * 2;
  constexpr size_t OFF_RP  = OFF_RT + (size_t)RMAX * 4;
  constexpr size_t OFF_TKI = OFF_RP + (size_t)RMAX * 4;
  constexpr size_t OFF_TKP = OFF_TKI + (size_t)T_TOK * 2 * 4;
  constexpr size_t OFF_CNT = OFF_TKP + (size_t)T_TOK * 2 * 4;
  constexpr size_t OFF_CUR = OFF_CNT + 256;
  // total ~352 MB

  unsigned short* xb  = (unsigned short*)(ws + OFF_XB);
  unsigned short* w1s = (unsigned short*)(ws + OFF_W1S);
  unsigned short* w2s = (unsigned short*)(ws + OFF_W2S);
  unsigned short* wps = (unsigned short*)(ws + OFF_WPS);
  unsigned short* h   = (unsigned short*)(ws + OFF_H);
  int*   rowtok = (int*)(ws + OFF_RT);
  float* rowp   = (float*)(ws + OFF_RP);
  int*   tki    = (int*)(ws + OFF_TKI);
  float* tkp    = (float*)(ws + OFF_TKP);
  int*   counts = (int*)(ws + OFF_CNT);
  int*   cursor = (int*)(ws + OFF_CUR);

  dim3 blk(256);
  k_init<<<dim3(8192), blk, 0, stream>>>(rowtok, rowp, counts, cursor, (float4*)outp);
  k_gate<<<dim3(T_TOK / 4), blk, 0, stream>>>(x, gw, nwt, noi, tki, tkp, counts, xb);
  k_convert_all<<<dim3(12288), blk, 0, stream>>>(w1, w2, wp, w1s, w2s, wps);
  k_scatter<<<dim3(T_TOK / 256), blk, 0, stream>>>(tki, tkp, counts, cursor, rowtok, rowp);
  k_gemm1<<<dim3(HDIM / 128, EEXP * 64), blk, 0, stream>>>(xb, w1s, w2s, b1, b2, counts, rowtok, h);
  k_gemm2<<<dim3(DDIM / 128, EEXP * 64), blk, 0, stream>>>(h, wps, bp, counts, rowtok, rowp, outp);
  (void)in_sizes; (void)n_in; (void)out_size; (void)ws_size;
}